// Round 5
// baseline (445.117 us; speedup 1.0000x reference)
//
#include <hip/hip_runtime.h>
#include <hip/hip_bf16.h>
#include <math.h>

#define H 1024
#define FF 2048
#define E 8
#define T 2048
#define NSLOT (2*T)
#define SLOT_PAD 128

#define WELEM (E*FF*H)          // 16,777,216 = 2^24 elems per weight tensor
#define XELEM (T*H)             // 2,097,152  = 2^21
#define TOT_CHUNKS ((3*(size_t)WELEM + XELEM) / 8)   // 8 elems per chunk
#define CONV_BLKS 2048
#define K1_BLKS (CONV_BLKS + T)

typedef __attribute__((ext_vector_type(8))) short s16x8;
typedef __attribute__((ext_vector_type(4))) float f32x4;
typedef __attribute__((ext_vector_type(4))) unsigned int u32x4;

static __device__ __forceinline__ unsigned short f2bf(float f) {
    union { float f; unsigned u; } v; v.f = f;
    unsigned r = v.u + 0x7fff + ((v.u >> 16) & 1);
    return (unsigned short)(r >> 16);
}
static __device__ __forceinline__ float bf2f(unsigned short s) {
    union { unsigned u; float f; } v; v.u = ((unsigned)s) << 16;
    return v.f;
}
static __device__ __forceinline__ unsigned pack2(float a, float b) {
    return (unsigned)f2bf(a) | ((unsigned)f2bf(b) << 16);
}
static __device__ __forceinline__ u32x4 pack8(f32x4 a, f32x4 b) {
    u32x4 r;
    r.x = pack2(a.x, a.y); r.y = pack2(a.z, a.w);
    r.z = pack2(b.x, b.y); r.w = pack2(b.z, b.w);
    return r;
}

typedef __attribute__((address_space(3))) unsigned int lds_uint;
typedef const __attribute__((address_space(1))) unsigned int glob_uint;
static __device__ __forceinline__ void gl_lds16(const void* g, void* l) {
    __builtin_amdgcn_global_load_lds((glob_uint*)g, (lds_uint*)l, 16, 0, 0);
}

static __device__ __forceinline__ void expert_range(const int* __restrict__ counts,
                                                    int e, int& off, int& cnt) {
    int acc = 0;
    #pragma unroll
    for (int i = 0; i < E; ++i) {
        int c = counts[i];
        if (i < e) acc += c;
        if (i == e) cnt = c;
    }
    off = acc;
}

// ---------------- K1: grid-stride convert (weights + x) + router ----------------
__global__ __launch_bounds__(256) void prep_kernel(
    const float* __restrict__ x, const float* __restrict__ gw,
    const float* __restrict__ w1, const float* __restrict__ w3,
    const float* __restrict__ w2,
    unsigned short* __restrict__ w1b, unsigned short* __restrict__ w3b,
    unsigned short* __restrict__ w2b, unsigned short* __restrict__ xb,
    float* __restrict__ logits_out, int* __restrict__ top_id,
    float* __restrict__ top_w, int* __restrict__ counts)
{
    int b = blockIdx.x;
    int tid = threadIdx.x;
    if (b < CONV_BLKS) {
        // grid-stride fp32->bf16 convert: per chunk = 8 elems, 32B read, 16B write.
        // tensor select via base>>24 (WELEM = 2^24, XELEM = 2^21, both chunk-aligned;
        // boundaries are block-aligned so the select is wave-uniform).
        for (size_t c = (size_t)b * 256 + tid; c < TOT_CHUNKS; c += (size_t)CONV_BLKS * 256) {
            size_t base = c * 8;
            int tsel = (int)(base >> 24);
            const float* s; unsigned short* d; size_t o;
            if (tsel == 0)      { s = w1; d = w1b; o = base; }
            else if (tsel == 1) { s = w3; d = w3b; o = base - (size_t)WELEM; }
            else if (tsel == 2) { s = w2; d = w2b; o = base - 2*(size_t)WELEM; }
            else                { s = x;  d = xb;  o = base - 3*(size_t)WELEM; }
            f32x4 a0 = *(const f32x4*)(s + o);
            f32x4 a1 = *(const f32x4*)(s + o + 4);
            *(u32x4*)(d + o) = pack8(a0, a1);
        }
        return;
    }
    // ---- router ----
    int t = b - CONV_BLKS;
    int e = tid >> 5;
    int l32 = tid & 31;
    const float* xr = x + (size_t)t * H;
    const float* gr = gw + (size_t)e * H;
    float s = 0.f;
    for (int h = l32; h < H; h += 32) s += xr[h] * gr[h];
    for (int off = 16; off; off >>= 1) s += __shfl_down(s, off, 32);
    __shared__ float lg[E];
    if (l32 == 0) lg[e] = s;
    __syncthreads();
    if (tid < E) logits_out[(size_t)t * E + tid] = lg[tid];
    if (tid == 0) {
        int i1 = 0; float b1 = lg[0];
        for (int i = 1; i < E; ++i) if (lg[i] > b1) { b1 = lg[i]; i1 = i; }
        int i2 = -1; float b2 = -INFINITY;
        for (int i = 0; i < E; ++i) if (i != i1 && lg[i] > b2) { b2 = lg[i]; i2 = i; }
        float p2 = expf(b2 - b1);
        float inv = 1.f / (1.f + p2);
        top_id[2*t]   = i1;  top_id[2*t+1] = i2;
        top_w[2*t]    = inv; top_w[2*t+1]  = p2 * inv;
        atomicAdd(&counts[i1], 1);
        atomicAdd(&counts[i2], 1);
    }
}

// ---------------- K2: slot assignment ----------------
__global__ __launch_bounds__(256) void assign_kernel(
    const int* __restrict__ top_id, const int* __restrict__ counts,
    int* __restrict__ cursors, int* __restrict__ top_pos,
    int* __restrict__ slot_token)
{
    int t = blockIdx.x * 256 + threadIdx.x;
    if (t >= T) return;
    int offs[E];
    {
        int acc = 0;
        #pragma unroll
        for (int i = 0; i < E; ++i) { offs[i] = acc; acc += counts[i]; }
    }
    #pragma unroll
    for (int k = 0; k < 2; ++k) {
        int e = top_id[2*t + k];
        int p = offs[e] + atomicAdd(&cursors[e], 1);
        top_pos[2*t + k] = p;
        slot_token[p] = t;
    }
}

// ---------------- K3: GEMM1 mid = silu(X@w1^T)*(X@w3^T) ----------------
// 128x128 output tile (per-wave 64x64 per tensor, acc 4x4) — m97 MFMA:read ratio.
// All-bf16 inputs via global_load_lds; 48 KB LDS single-buffer, 2-barrier loop.
__global__ __launch_bounds__(256) void gemm1_kernel(
    const unsigned short* __restrict__ xb, const int* __restrict__ slot_token,
    const unsigned short* __restrict__ w1b, const unsigned short* __restrict__ w3b,
    const int* __restrict__ counts, unsigned short* __restrict__ mid)
{
    int e = blockIdx.z;
    int off, cnt;
    expert_range(counts, e, off, cnt);
    int m0 = blockIdx.y * 128;
    if (m0 >= cnt) return;
    int f0 = blockIdx.x * 128;

    __shared__ __align__(16) unsigned short sx[128 * 64];
    __shared__ __align__(16) unsigned short s1[128 * 64];
    __shared__ __align__(16) unsigned short s3[128 * 64];

    int tid = threadIdx.x;
    int wv = tid >> 6, ln = tid & 63;
    int quad = ln >> 4, l16 = ln & 15;
    int wm = wv & 1, wn = wv >> 1;          // 2m x 2n waves, 64x64 each
    int xor7 = l16 & 7;

    // A staging: indirect token gather, pre-swizzled source (proven layout)
    const unsigned short* xsrc[4]; unsigned short* xdst[4];
    #pragma unroll
    for (int j = 0; j < 4; ++j) {
        int row = wv * 32 + j * 8 + (ln >> 3);
        int slot = off + m0 + row;
        if (m0 + row >= cnt) slot = off;          // clamp to a valid slot
        int tok = slot_token[slot];
        int cl = (ln & 7) ^ (row & 7);
        xsrc[j] = xb + (size_t)tok * H + cl * 8;
        xdst[j] = &sx[(wv * 32 + j * 8) * 64];
    }
    // B staging: 128 rows each of w1b/w3b per tile (4 issues/wave/tensor)
    const unsigned short *w1s[4], *w3s[4]; unsigned short *d1[4], *d3[4];
    #pragma unroll
    for (int j = 0; j < 4; ++j) {
        int row = wv * 32 + j * 8 + (ln >> 3);
        int cl = (ln & 7) ^ (row & 7);
        w1s[j] = w1b + ((size_t)e * FF + f0 + row) * H + cl * 8;
        w3s[j] = w3b + ((size_t)e * FF + f0 + row) * H + cl * 8;
        d1[j] = &s1[(wv * 32 + j * 8) * 64];
        d3[j] = &s3[(wv * 32 + j * 8) * 64];
    }

    f32x4 acc1[4][4], acc3[4][4];
    #pragma unroll
    for (int i = 0; i < 4; ++i)
        #pragma unroll
        for (int j = 0; j < 4; ++j) {
            acc1[i][j] = (f32x4){0.f, 0.f, 0.f, 0.f};
            acc3[i][j] = (f32x4){0.f, 0.f, 0.f, 0.f};
        }

    for (int k0 = 0; k0 < H; k0 += 64) {
        #pragma unroll
        for (int j = 0; j < 4; ++j) {
            gl_lds16(xsrc[j] + k0, xdst[j]);
            gl_lds16(w1s[j] + k0, d1[j]);
            gl_lds16(w3s[j] + k0, d3[j]);
        }
        __syncthreads();
        #pragma unroll
        for (int ks = 0; ks < 2; ++ks) {
            int cph = ((quad + 4 * ks) ^ xor7) << 3;
            s16x8 a[4], b1v[4], b3v[4];
            #pragma unroll
            for (int i = 0; i < 4; ++i)
                a[i] = *(const s16x8*)&sx[(wm * 64 + i * 16 + l16) * 64 + cph];
            #pragma unroll
            for (int j = 0; j < 4; ++j) {
                b1v[j] = *(const s16x8*)&s1[(wn * 64 + j * 16 + l16) * 64 + cph];
                b3v[j] = *(const s16x8*)&s3[(wn * 64 + j * 16 + l16) * 64 + cph];
            }
            #pragma unroll
            for (int i = 0; i < 4; ++i)
                #pragma unroll
                for (int j = 0; j < 4; ++j) {
                    acc1[i][j] = __builtin_amdgcn_mfma_f32_16x16x32_bf16(a[i], b1v[j], acc1[i][j], 0, 0, 0);
                    acc3[i][j] = __builtin_amdgcn_mfma_f32_16x16x32_bf16(a[i], b3v[j], acc3[i][j], 0, 0, 0);
                }
        }
        __syncthreads();
    }

    #pragma unroll
    for (int i = 0; i < 4; ++i) {
        #pragma unroll
        for (int r = 0; r < 4; ++r) {
            int row = wm * 64 + i * 16 + quad * 4 + r;
            if (m0 + row < cnt) {
                size_t base = (size_t)(off + m0 + row) * FF + f0 + wn * 64;
                #pragma unroll
                for (int j = 0; j < 4; ++j) {
                    float h = acc1[i][j][r];
                    float g = acc3[i][j][r];
                    float v = h / (1.f + __expf(-h)) * g;
                    mid[base + j * 16 + l16] = f2bf(v);
                }
            }
        }
    }
}

// ---------------- K4: GEMM2 y[slot] = mid[slot] @ w2^T ----------------
// Plain 128x128 bf16 GEMM, K=FF, 32 KB LDS single-buffer.
__global__ __launch_bounds__(256) void gemm2_kernel(
    const unsigned short* __restrict__ mid, const unsigned short* __restrict__ w2b,
    const int* __restrict__ counts, unsigned short* __restrict__ y)
{
    int e = blockIdx.z;
    int off, cnt;
    expert_range(counts, e, off, cnt);
    int m0 = blockIdx.y * 128;
    if (m0 >= cnt) return;
    int n0 = blockIdx.x * 128;

    __shared__ __align__(16) unsigned short sa[128 * 64];
    __shared__ __align__(16) unsigned short sb[128 * 64];

    int tid = threadIdx.x;
    int wv = tid >> 6, ln = tid & 63;
    int quad = ln >> 4, l16 = ln & 15;
    int wm = wv & 1, wn = wv >> 1;
    int xor7 = l16 & 7;

    const unsigned short* asrc[4]; unsigned short* adst[4];
    #pragma unroll
    for (int j = 0; j < 4; ++j) {
        int row = wv * 32 + j * 8 + (ln >> 3);
        int cl = (ln & 7) ^ (row & 7);
        asrc[j] = mid + (size_t)(off + m0 + row) * FF + cl * 8;
        adst[j] = &sa[(wv * 32 + j * 8) * 64];
    }
    const unsigned short* bsrc[4]; unsigned short* bdst[4];
    #pragma unroll
    for (int j = 0; j < 4; ++j) {
        int row = wv * 32 + j * 8 + (ln >> 3);
        int cl = (ln & 7) ^ (row & 7);
        bsrc[j] = w2b + ((size_t)e * H + n0 + row) * FF + cl * 8;
        bdst[j] = &sb[(wv * 32 + j * 8) * 64];
    }

    f32x4 acc[4][4];
    #pragma unroll
    for (int i = 0; i < 4; ++i)
        #pragma unroll
        for (int j = 0; j < 4; ++j) acc[i][j] = (f32x4){0.f, 0.f, 0.f, 0.f};

    for (int k0 = 0; k0 < FF; k0 += 64) {
        #pragma unroll
        for (int j = 0; j < 4; ++j) {
            gl_lds16(asrc[j] + k0, adst[j]);
            gl_lds16(bsrc[j] + k0, bdst[j]);
        }
        __syncthreads();
        #pragma unroll
        for (int ks = 0; ks < 2; ++ks) {
            int cph = ((quad + 4 * ks) ^ xor7) << 3;
            s16x8 a[4], b[4];
            #pragma unroll
            for (int i = 0; i < 4; ++i)
                a[i] = *(const s16x8*)&sa[(wm * 64 + i * 16 + l16) * 64 + cph];
            #pragma unroll
            for (int j = 0; j < 4; ++j)
                b[j] = *(const s16x8*)&sb[(wn * 64 + j * 16 + l16) * 64 + cph];
            #pragma unroll
            for (int i = 0; i < 4; ++i)
                #pragma unroll
                for (int j = 0; j < 4; ++j)
                    acc[i][j] = __builtin_amdgcn_mfma_f32_16x16x32_bf16(a[i], b[j], acc[i][j], 0, 0, 0);
        }
        __syncthreads();
    }

    #pragma unroll
    for (int i = 0; i < 4; ++i) {
        #pragma unroll
        for (int r = 0; r < 4; ++r) {
            int row = wm * 64 + i * 16 + quad * 4 + r;
            if (m0 + row < cnt) {
                size_t base = (size_t)(off + m0 + row) * H + n0 + wn * 64;
                #pragma unroll
                for (int j = 0; j < 4; ++j)
                    y[base + j * 16 + l16] = f2bf(acc[i][j][r]);
            }
        }
    }
}

// ---------------- K5: combine out[t] = w0*y[p0] + w1*y[p1] ----------------
__global__ __launch_bounds__(256) void combine_kernel(
    const unsigned short* __restrict__ y, const int* __restrict__ top_pos,
    const float* __restrict__ top_w, float* __restrict__ out)
{
    int t = blockIdx.x, tid = threadIdx.x;
    int p0 = top_pos[2*t], p1 = top_pos[2*t+1];
    float w0 = top_w[2*t], w1 = top_w[2*t+1];
    ushort4 a = ((const ushort4*)(y + (size_t)p0 * H))[tid];
    ushort4 b = ((const ushort4*)(y + (size_t)p1 * H))[tid];
    float4 o;
    o.x = w0 * bf2f(a.x) + w1 * bf2f(b.x);
    o.y = w0 * bf2f(a.y) + w1 * bf2f(b.y);
    o.z = w0 * bf2f(a.z) + w1 * bf2f(b.z);
    o.w = w0 * bf2f(a.w) + w1 * bf2f(b.w);
    ((float4*)(out + (size_t)t * H))[tid] = o;
}

extern "C" void kernel_launch(void* const* d_in, const int* in_sizes, int n_in,
                              void* d_out, int out_size, void* d_ws, size_t ws_size,
                              hipStream_t stream) {
    const float* x  = (const float*)d_in[0];
    const float* gw = (const float*)d_in[1];
    const float* w1 = (const float*)d_in[2];
    const float* w2 = (const float*)d_in[3];
    const float* w3 = (const float*)d_in[4];
    float* out    = (float*)d_out;              // T*H
    float* logits = out + (size_t)T * H;        // T*E

    // workspace layout
    int* counts      = (int*)d_ws;              // [8]
    int* cursors     = counts + 8;              // [8]
    int* top_id      = counts + 16;             // [2T]
    int* top_pos     = top_id + 2*T;            // [2T]
    int* slot_token  = top_pos + 2*T;           // [NSLOT]
    float* top_w     = (float*)(slot_token + NSLOT);               // [2T]
    unsigned short* xb  = (unsigned short*)(top_w + 2*T);          // [T][H]
    unsigned short* mid = xb  + (size_t)T * H;                     // [NSLOT+PAD][FF]
    unsigned short* y   = mid + (size_t)(NSLOT + SLOT_PAD) * FF;   // [NSLOT][H]
    unsigned short* w1b = y   + (size_t)NSLOT * H;                 // [E*FF*H]
    unsigned short* w3b = w1b + (size_t)WELEM;
    unsigned short* w2b = w3b + (size_t)WELEM;

    (void)hipMemsetAsync(counts, 0, 16 * sizeof(int), stream);

    prep_kernel<<<K1_BLKS, 256, 0, stream>>>(x, gw, w1, w3, w2,
                                             w1b, w3b, w2b, xb,
                                             logits, top_id, top_w, counts);
    assign_kernel<<<(T + 255) / 256, 256, 0, stream>>>(top_id, counts, cursors,
                                                       top_pos, slot_token);
    gemm1_kernel<<<dim3(FF / 128, 16, E), 256, 0, stream>>>(xb, slot_token,
                                                            w1b, w3b, counts, mid);
    gemm2_kernel<<<dim3(H / 128, 16, E), 256, 0, stream>>>(mid, w2b, counts, y);
    combine_kernel<<<T, 256, 0, stream>>>(y, top_pos, top_w, out);
}

// Round 6
// 429.687 us; speedup vs baseline: 1.0359x; 1.0359x over previous
//
#include <hip/hip_runtime.h>
#include <hip/hip_bf16.h>
#include <math.h>

#define H 1024
#define FF 2048
#define E 8
#define T 2048
#define NSLOT (2*T)
#define SLOT_PAD 128

#define WELEM (E*FF*H)          // 16,777,216 elems per weight tensor
#define XELEM (T*H)             // 2,097,152
#define WCONV_BLKS 6144         // 3 tensors x 2048 blocks x 8192 elems
#define CONV_BLKS 6400          // + 256 blocks for x

typedef __attribute__((ext_vector_type(8))) short s16x8;
typedef __attribute__((ext_vector_type(4))) float f32x4;
typedef __attribute__((ext_vector_type(4))) unsigned int u32x4;

static __device__ __forceinline__ unsigned short f2bf(float f) {
    union { float f; unsigned u; } v; v.f = f;
    unsigned r = v.u + 0x7fff + ((v.u >> 16) & 1);
    return (unsigned short)(r >> 16);
}
static __device__ __forceinline__ float bf2f(unsigned short s) {
    union { unsigned u; float f; } v; v.u = ((unsigned)s) << 16;
    return v.f;
}
static __device__ __forceinline__ unsigned pack2(float a, float b) {
    return (unsigned)f2bf(a) | ((unsigned)f2bf(b) << 16);
}

typedef __attribute__((address_space(3))) unsigned int lds_uint;
typedef const __attribute__((address_space(1))) unsigned int glob_uint;
static __device__ __forceinline__ void gl_lds16(const void* g, void* l) {
    __builtin_amdgcn_global_load_lds((glob_uint*)g, (lds_uint*)l, 16, 0, 0);
}

static __device__ __forceinline__ void expert_range(const int* __restrict__ counts,
                                                    int e, int& off, int& cnt) {
    int acc = 0;
    #pragma unroll
    for (int i = 0; i < E; ++i) {
        int c = counts[i];
        if (i < e) acc += c;
        if (i == e) cnt = c;
    }
    off = acc;
}

// ---------------- K0: fp32->bf16 convert, max MLP ----------------
// Per block: 8192 elems. Per thread: 8 independent fully-contiguous 16B NT
// loads (lane i at stripe_base + i*16B) + 8 contiguous 8B stores.
// NT on loads: fp32 weights are never re-read -> don't pollute L2/L3.
// Plain stores: bf16 outputs ARE re-read by the GEMMs -> keep cacheable.
__global__ __launch_bounds__(256) void conv_kernel(
    const float* __restrict__ w1, const float* __restrict__ w3,
    const float* __restrict__ w2, const float* __restrict__ x,
    unsigned short* __restrict__ w1b, unsigned short* __restrict__ w3b,
    unsigned short* __restrict__ w2b, unsigned short* __restrict__ xb)
{
    int b = blockIdx.x, tid = threadIdx.x;
    int r = b >> 11;                       // 0,1,2 = weights; 3 = x
    const float* s = (r == 0) ? w1 : (r == 1) ? w3 : (r == 2) ? w2 : x;
    unsigned short* d = (r == 0) ? w1b : (r == 1) ? w3b : (r == 2) ? w2b : xb;
    size_t base = (size_t)(b & 2047) * 8192;   // for r==3, b-6144 == b&2047 (<256)

    f32x4 a[8];
    #pragma unroll
    for (int j = 0; j < 8; ++j)
        a[j] = __builtin_nontemporal_load((const f32x4*)(s + base + (size_t)(j * 256 + tid) * 4));
    #pragma unroll
    for (int j = 0; j < 8; ++j) {
        uint2 rr;
        rr.x = pack2(a[j].x, a[j].y);
        rr.y = pack2(a[j].z, a[j].w);
        *(uint2*)(d + base + (size_t)(j * 256 + tid) * 4) = rr;
    }
}

// ---------------- K1: router (standalone for attribution) ----------------
__global__ __launch_bounds__(256) void router_kernel(
    const float* __restrict__ x, const float* __restrict__ gw,
    float* __restrict__ logits_out, int* __restrict__ top_id,
    float* __restrict__ top_w, int* __restrict__ counts)
{
    int t = blockIdx.x;
    int tid = threadIdx.x;
    int e = tid >> 5;
    int l32 = tid & 31;
    const float* xr = x + (size_t)t * H;
    const float* gr = gw + (size_t)e * H;
    float s = 0.f;
    for (int h = l32; h < H; h += 32) s += xr[h] * gr[h];
    for (int off = 16; off; off >>= 1) s += __shfl_down(s, off, 32);
    __shared__ float lg[E];
    if (l32 == 0) lg[e] = s;
    __syncthreads();
    if (tid < E) logits_out[(size_t)t * E + tid] = lg[tid];
    if (tid == 0) {
        int i1 = 0; float b1 = lg[0];
        for (int i = 1; i < E; ++i) if (lg[i] > b1) { b1 = lg[i]; i1 = i; }
        int i2 = -1; float b2 = -INFINITY;
        for (int i = 0; i < E; ++i) if (i != i1 && lg[i] > b2) { b2 = lg[i]; i2 = i; }
        float p2 = expf(b2 - b1);
        float inv = 1.f / (1.f + p2);
        top_id[2*t]   = i1;  top_id[2*t+1] = i2;
        top_w[2*t]    = inv; top_w[2*t+1]  = p2 * inv;
        atomicAdd(&counts[i1], 1);
        atomicAdd(&counts[i2], 1);
    }
}

// ---------------- K2: slot assignment ----------------
__global__ __launch_bounds__(256) void assign_kernel(
    const int* __restrict__ top_id, const int* __restrict__ counts,
    int* __restrict__ cursors, int* __restrict__ top_pos,
    int* __restrict__ slot_token)
{
    int t = blockIdx.x * 256 + threadIdx.x;
    if (t >= T) return;
    int offs[E];
    {
        int acc = 0;
        #pragma unroll
        for (int i = 0; i < E; ++i) { offs[i] = acc; acc += counts[i]; }
    }
    #pragma unroll
    for (int k = 0; k < 2; ++k) {
        int e = top_id[2*t + k];
        int p = offs[e] + atomicAdd(&cursors[e], 1);
        top_pos[2*t + k] = p;
        slot_token[p] = t;
    }
}

// ---------------- K3: GEMM1 mid = silu(X@w1^T)*(X@w3^T) ----------------
// 128x128 output tile (per-wave 64x64 per tensor, acc 4x4) — m97 MFMA:read ratio.
// All-bf16 inputs via global_load_lds; 48 KB LDS single-buffer, 2-barrier loop.
__global__ __launch_bounds__(256) void gemm1_kernel(
    const unsigned short* __restrict__ xb, const int* __restrict__ slot_token,
    const unsigned short* __restrict__ w1b, const unsigned short* __restrict__ w3b,
    const int* __restrict__ counts, unsigned short* __restrict__ mid)
{
    int e = blockIdx.z;
    int off, cnt;
    expert_range(counts, e, off, cnt);
    int m0 = blockIdx.y * 128;
    if (m0 >= cnt) return;
    int f0 = blockIdx.x * 128;

    __shared__ __align__(16) unsigned short sx[128 * 64];
    __shared__ __align__(16) unsigned short s1[128 * 64];
    __shared__ __align__(16) unsigned short s3[128 * 64];

    int tid = threadIdx.x;
    int wv = tid >> 6, ln = tid & 63;
    int quad = ln >> 4, l16 = ln & 15;
    int wm = wv & 1, wn = wv >> 1;          // 2m x 2n waves, 64x64 each
    int xor7 = l16 & 7;

    const unsigned short* xsrc[4]; unsigned short* xdst[4];
    #pragma unroll
    for (int j = 0; j < 4; ++j) {
        int row = wv * 32 + j * 8 + (ln >> 3);
        int slot = off + m0 + row;
        if (m0 + row >= cnt) slot = off;          // clamp to a valid slot
        int tok = slot_token[slot];
        int cl = (ln & 7) ^ (row & 7);
        xsrc[j] = xb + (size_t)tok * H + cl * 8;
        xdst[j] = &sx[(wv * 32 + j * 8) * 64];
    }
    const unsigned short *w1s[4], *w3s[4]; unsigned short *d1[4], *d3[4];
    #pragma unroll
    for (int j = 0; j < 4; ++j) {
        int row = wv * 32 + j * 8 + (ln >> 3);
        int cl = (ln & 7) ^ (row & 7);
        w1s[j] = w1b + ((size_t)e * FF + f0 + row) * H + cl * 8;
        w3s[j] = w3b + ((size_t)e * FF + f0 + row) * H + cl * 8;
        d1[j] = &s1[(wv * 32 + j * 8) * 64];
        d3[j] = &s3[(wv * 32 + j * 8) * 64];
    }

    f32x4 acc1[4][4], acc3[4][4];
    #pragma unroll
    for (int i = 0; i < 4; ++i)
        #pragma unroll
        for (int j = 0; j < 4; ++j) {
            acc1[i][j] = (f32x4){0.f, 0.f, 0.f, 0.f};
            acc3[i][j] = (f32x4){0.f, 0.f, 0.f, 0.f};
        }

    for (int k0 = 0; k0 < H; k0 += 64) {
        #pragma unroll
        for (int j = 0; j < 4; ++j) {
            gl_lds16(xsrc[j] + k0, xdst[j]);
            gl_lds16(w1s[j] + k0, d1[j]);
            gl_lds16(w3s[j] + k0, d3[j]);
        }
        __syncthreads();
        #pragma unroll
        for (int ks = 0; ks < 2; ++ks) {
            int cph = ((quad + 4 * ks) ^ xor7) << 3;
            s16x8 a[4], b1v[4], b3v[4];
            #pragma unroll
            for (int i = 0; i < 4; ++i)
                a[i] = *(const s16x8*)&sx[(wm * 64 + i * 16 + l16) * 64 + cph];
            #pragma unroll
            for (int j = 0; j < 4; ++j) {
                b1v[j] = *(const s16x8*)&s1[(wn * 64 + j * 16 + l16) * 64 + cph];
                b3v[j] = *(const s16x8*)&s3[(wn * 64 + j * 16 + l16) * 64 + cph];
            }
            #pragma unroll
            for (int i = 0; i < 4; ++i)
                #pragma unroll
                for (int j = 0; j < 4; ++j) {
                    acc1[i][j] = __builtin_amdgcn_mfma_f32_16x16x32_bf16(a[i], b1v[j], acc1[i][j], 0, 0, 0);
                    acc3[i][j] = __builtin_amdgcn_mfma_f32_16x16x32_bf16(a[i], b3v[j], acc3[i][j], 0, 0, 0);
                }
        }
        __syncthreads();
    }

    #pragma unroll
    for (int i = 0; i < 4; ++i) {
        #pragma unroll
        for (int r = 0; r < 4; ++r) {
            int row = wm * 64 + i * 16 + quad * 4 + r;
            if (m0 + row < cnt) {
                size_t base = (size_t)(off + m0 + row) * FF + f0 + wn * 64;
                #pragma unroll
                for (int j = 0; j < 4; ++j) {
                    float h = acc1[i][j][r];
                    float g = acc3[i][j][r];
                    float v = h / (1.f + __expf(-h)) * g;
                    mid[base + j * 16 + l16] = f2bf(v);
                }
            }
        }
    }
}

// ---------------- K4: GEMM2 y[slot] = mid[slot] @ w2^T ----------------
__global__ __launch_bounds__(256) void gemm2_kernel(
    const unsigned short* __restrict__ mid, const unsigned short* __restrict__ w2b,
    const int* __restrict__ counts, unsigned short* __restrict__ y)
{
    int e = blockIdx.z;
    int off, cnt;
    expert_range(counts, e, off, cnt);
    int m0 = blockIdx.y * 128;
    if (m0 >= cnt) return;
    int n0 = blockIdx.x * 128;

    __shared__ __align__(16) unsigned short sa[128 * 64];
    __shared__ __align__(16) unsigned short sb[128 * 64];

    int tid = threadIdx.x;
    int wv = tid >> 6, ln = tid & 63;
    int quad = ln >> 4, l16 = ln & 15;
    int wm = wv & 1, wn = wv >> 1;
    int xor7 = l16 & 7;

    const unsigned short* asrc[4]; unsigned short* adst[4];
    #pragma unroll
    for (int j = 0; j < 4; ++j) {
        int row = wv * 32 + j * 8 + (ln >> 3);
        int cl = (ln & 7) ^ (row & 7);
        asrc[j] = mid + (size_t)(off + m0 + row) * FF + cl * 8;
        adst[j] = &sa[(wv * 32 + j * 8) * 64];
    }
    const unsigned short* bsrc[4]; unsigned short* bdst[4];
    #pragma unroll
    for (int j = 0; j < 4; ++j) {
        int row = wv * 32 + j * 8 + (ln >> 3);
        int cl = (ln & 7) ^ (row & 7);
        bsrc[j] = w2b + ((size_t)e * H + n0 + row) * FF + cl * 8;
        bdst[j] = &sb[(wv * 32 + j * 8) * 64];
    }

    f32x4 acc[4][4];
    #pragma unroll
    for (int i = 0; i < 4; ++i)
        #pragma unroll
        for (int j = 0; j < 4; ++j) acc[i][j] = (f32x4){0.f, 0.f, 0.f, 0.f};

    for (int k0 = 0; k0 < FF; k0 += 64) {
        #pragma unroll
        for (int j = 0; j < 4; ++j) {
            gl_lds16(asrc[j] + k0, adst[j]);
            gl_lds16(bsrc[j] + k0, bdst[j]);
        }
        __syncthreads();
        #pragma unroll
        for (int ks = 0; ks < 2; ++ks) {
            int cph = ((quad + 4 * ks) ^ xor7) << 3;
            s16x8 a[4], b[4];
            #pragma unroll
            for (int i = 0; i < 4; ++i)
                a[i] = *(const s16x8*)&sa[(wm * 64 + i * 16 + l16) * 64 + cph];
            #pragma unroll
            for (int j = 0; j < 4; ++j)
                b[j] = *(const s16x8*)&sb[(wn * 64 + j * 16 + l16) * 64 + cph];
            #pragma unroll
            for (int i = 0; i < 4; ++i)
                #pragma unroll
                for (int j = 0; j < 4; ++j)
                    acc[i][j] = __builtin_amdgcn_mfma_f32_16x16x32_bf16(a[i], b[j], acc[i][j], 0, 0, 0);
        }
        __syncthreads();
    }

    #pragma unroll
    for (int i = 0; i < 4; ++i) {
        #pragma unroll
        for (int r = 0; r < 4; ++r) {
            int row = wm * 64 + i * 16 + quad * 4 + r;
            if (m0 + row < cnt) {
                size_t base = (size_t)(off + m0 + row) * H + n0 + wn * 64;
                #pragma unroll
                for (int j = 0; j < 4; ++j)
                    y[base + j * 16 + l16] = f2bf(acc[i][j][r]);
            }
        }
    }
}

// ---------------- K5: combine out[t] = w0*y[p0] + w1*y[p1] ----------------
__global__ __launch_bounds__(256) void combine_kernel(
    const unsigned short* __restrict__ y, const int* __restrict__ top_pos,
    const float* __restrict__ top_w, float* __restrict__ out)
{
    int t = blockIdx.x, tid = threadIdx.x;
    int p0 = top_pos[2*t], p1 = top_pos[2*t+1];
    float w0 = top_w[2*t], w1 = top_w[2*t+1];
    ushort4 a = ((const ushort4*)(y + (size_t)p0 * H))[tid];
    ushort4 b = ((const ushort4*)(y + (size_t)p1 * H))[tid];
    float4 o;
    o.x = w0 * bf2f(a.x) + w1 * bf2f(b.x);
    o.y = w0 * bf2f(a.y) + w1 * bf2f(b.y);
    o.z = w0 * bf2f(a.z) + w1 * bf2f(b.z);
    o.w = w0 * bf2f(a.w) + w1 * bf2f(b.w);
    ((float4*)(out + (size_t)t * H))[tid] = o;
}

extern "C" void kernel_launch(void* const* d_in, const int* in_sizes, int n_in,
                              void* d_out, int out_size, void* d_ws, size_t ws_size,
                              hipStream_t stream) {
    const float* x  = (const float*)d_in[0];
    const float* gw = (const float*)d_in[1];
    const float* w1 = (const float*)d_in[2];
    const float* w2 = (const float*)d_in[3];
    const float* w3 = (const float*)d_in[4];
    float* out    = (float*)d_out;              // T*H
    float* logits = out + (size_t)T * H;        // T*E

    // workspace layout
    int* counts      = (int*)d_ws;              // [8]
    int* cursors     = counts + 8;              // [8]
    int* top_id      = counts + 16;             // [2T]
    int* top_pos     = top_id + 2*T;            // [2T]
    int* slot_token  = top_pos + 2*T;           // [NSLOT]
    float* top_w     = (float*)(slot_token + NSLOT);               // [2T]
    unsigned short* xb  = (unsigned short*)(top_w + 2*T);          // [T][H]
    unsigned short* mid = xb  + (size_t)T * H;                     // [NSLOT+PAD][FF]
    unsigned short* y   = mid + (size_t)(NSLOT + SLOT_PAD) * FF;   // [NSLOT][H]
    unsigned short* w1b = y   + (size_t)NSLOT * H;                 // [E*FF*H]
    unsigned short* w3b = w1b + (size_t)WELEM;
    unsigned short* w2b = w3b + (size_t)WELEM;

    (void)hipMemsetAsync(counts, 0, 16 * sizeof(int), stream);

    conv_kernel<<<CONV_BLKS, 256, 0, stream>>>(w1, w3, w2, x, w1b, w3b, w2b, xb);
    router_kernel<<<T, 256, 0, stream>>>(x, gw, logits, top_id, top_w, counts);
    assign_kernel<<<(T + 255) / 256, 256, 0, stream>>>(top_id, counts, cursors,
                                                       top_pos, slot_token);
    gemm1_kernel<<<dim3(FF / 128, 16, E), 256, 0, stream>>>(xb, slot_token,
                                                            w1b, w3b, counts, mid);
    gemm2_kernel<<<dim3(H / 128, 16, E), 256, 0, stream>>>(mid, w2b, counts, y);
    combine_kernel<<<T, 256, 0, stream>>>(y, top_pos, top_w, out);
}